// Round 1
// baseline (2248.573 us; speedup 1.0000x reference)
//
#include <hip/hip_runtime.h>
#include <hip/hip_bf16.h>
#include <math.h>

// Problem constants (from reference)
constexpr int Bb   = 32;
constexpr int Ls   = 110;
constexpr int Gs   = 512;
constexpr int Ns   = 40;
constexpr int Ds   = 300;
constexpr int WPc  = 10;
constexpr int WFc  = 10;
constexpr int MAXNc = 110;
constexpr float EPSf  = 1e-8f;
constexpr float CLIPf = 1.0f - 1e-6f;
constexpr int BL = Bb * Ls;        // 3520

// ---------------------------------------------------------------------------
// Kernel 0: transpose W_sem (512x512) so the sem GEMM reads it coalesced.
// ---------------------------------------------------------------------------
__global__ __launch_bounds__(256) void transpose_wsem(const float* __restrict__ w,
                                                      float* __restrict__ wt) {
  __shared__ float tile[32][33];
  const int bx = blockIdx.x * 32;
  const int by = blockIdx.y * 32;
  const int tx = threadIdx.x;   // 0..31
  const int ty = threadIdx.y;   // 0..7
#pragma unroll
  for (int r = ty; r < 32; r += 8)
    tile[r][tx] = w[(by + r) * Gs + (bx + tx)];
  __syncthreads();
#pragma unroll
  for (int r = ty; r < 32; r += 8)
    wt[(bx + r) * Gs + (by + tx)] = tile[tx][r];   // wt[t][s] = w[s][t]
}

// ---------------------------------------------------------------------------
// Kernel 1: att_sem[bl,s] = sum_t W[s,t] * x[bl,t]  (= sum_t WT[t,s]*x[bl,t])
// Block: 512 threads (thread = s), 8 bl-rows per block. x reads are
// block-uniform -> scalar loads; WT reads coalesced across s.
// Also emits na[bl] = max(||att_sem row||, EPS).
// ---------------------------------------------------------------------------
__global__ __launch_bounds__(512) void sem_gemm(const float* __restrict__ nf,
                                                const float* __restrict__ wt,
                                                float* __restrict__ att_sem,
                                                float* __restrict__ na_arr) {
  const int bl0 = blockIdx.x * 8;
  const int s = threadIdx.x;
  const float* __restrict__ x0 = nf + (size_t)bl0 * Gs;
  float acc[8];
#pragma unroll
  for (int r = 0; r < 8; ++r) acc[r] = 0.f;
#pragma unroll 4
  for (int t = 0; t < Gs; ++t) {
    const float wv = wt[t * Gs + s];
#pragma unroll
    for (int r = 0; r < 8; ++r) acc[r] = fmaf(wv, x0[r * Gs + t], acc[r]);
  }
#pragma unroll
  for (int r = 0; r < 8; ++r) att_sem[(size_t)(bl0 + r) * Gs + s] = acc[r];

  __shared__ float partial[8][8];
  const int wave = s >> 6, lane = s & 63;
#pragma unroll
  for (int r = 0; r < 8; ++r) {
    float v = acc[r] * acc[r];
#pragma unroll
    for (int off = 32; off > 0; off >>= 1) v += __shfl_xor(v, off);
    if (lane == 0) partial[r][wave] = v;
  }
  __syncthreads();
  if (s < 8) {
    float sum = 0.f;
#pragma unroll
    for (int w2 = 0; w2 < 8; ++w2) sum += partial[s][w2];
    na_arr[bl0 + s] = fmaxf(sqrtf(sum), EPSf);
  }
}

// ---------------------------------------------------------------------------
// Kernel 2: banded semantic attention + softmax. One block per (b,j).
// Writes the FULL output row (zeros outside the window) -> also serves as
// the out zero-init. con_attn later does "+=" on masked entries.
// ---------------------------------------------------------------------------
__global__ __launch_bounds__(256) void sem_attn(const float* __restrict__ nf,
                                                const float* __restrict__ att_sem,
                                                const float* __restrict__ na_arr,
                                                const int* __restrict__ tlen,
                                                float* __restrict__ out) {
  const int blk = blockIdx.x;
  const int b = blk / Ls, j = blk % Ls;
  const int len = tlen[b];
  float* __restrict__ orow = out + (size_t)(b * Ls + j) * MAXNc;
  if (j >= len) {
    for (int k = threadIdx.x; k < MAXNc; k += 256) orow[k] = 0.f;
    return;
  }
  const int k0 = max(j - WPc, 0);
  const int k1 = min(j + WFc, len - 1);
  const int nk = k1 - k0 + 1;   // <= 21

  __shared__ float xs[Gs];
  __shared__ float sc[21];
  __shared__ float red[4];

  // stage x = nf[b,j,:] and reduce ||x||^2
  const float* __restrict__ x = nf + (size_t)(b * Ls + j) * Gs;
  float ss = 0.f;
  for (int t = threadIdx.x; t < Gs; t += 256) {
    const float v = x[t];
    xs[t] = v;
    ss += v * v;
  }
  const int wave = threadIdx.x >> 6, lane = threadIdx.x & 63;
#pragma unroll
  for (int off = 32; off > 0; off >>= 1) ss += __shfl_xor(ss, off);
  if (lane == 0) red[wave] = ss;
  __syncthreads();
  const float nfn = fmaxf(sqrtf(red[0] + red[1] + red[2] + red[3]), EPSf);

  // banded dots: wave w handles window indices w, w+4, ...
  for (int i = wave; i < nk; i += 4) {
    const int k = k0 + i;
    const float* __restrict__ as = att_sem + (size_t)(b * Ls + k) * Gs;
    float d = 0.f;
#pragma unroll
    for (int t = lane; t < Gs; t += 64) d = fmaf(xs[t], as[t], d);
#pragma unroll
    for (int off = 32; off > 0; off >>= 1) d += __shfl_xor(d, off);
    if (lane == 0) {
      float cs = d / (nfn * na_arr[b * Ls + k]);
      cs = fminf(fmaxf(cs, -CLIPf), CLIPf);
      sc[i] = 1.0f - acosf(cs) * (float)(1.0 / M_PI);
    }
  }
  __syncthreads();
  if (threadIdx.x == 0) {
    float m = -1e30f;
    for (int i = 0; i < nk; ++i) m = fmaxf(m, sc[i]);
    red[0] = m;
  }
  __syncthreads();
  const float m = red[0];
  if ((int)threadIdx.x < nk) sc[threadIdx.x] = expf(sc[threadIdx.x] - m);
  __syncthreads();
  if (threadIdx.x == 0) {
    float s = 0.f;
    for (int i = 0; i < nk; ++i) s += sc[i];
    red[1] = 1.0f / fmaxf(s, EPSf);
  }
  __syncthreads();
  const float inv = red[1];
  for (int k = threadIdx.x; k < MAXNc; k += 256) {
    float v = 0.f;
    if (k >= k0 && k <= k1) v = 0.5f * sc[k - k0] * inv;
    orow[k] = v;
  }
}

// ---------------------------------------------------------------------------
// Kernel 3: the 25 GF matmul. Per (b,l) block: Y[n,t] = sum_s K[n,s]*Wc[s,t].
// K reads are block-uniform -> scalar (s_load_dwordx4) broadcast; Wc column
// loads coalesced (Wc is 360 KB, L2-resident). Then normalize rows:
// ybar = aff*Y / max(aff*||Y||, EPS) stored as bf16; nk_inv = 1/max(||K||,EPS).
// Early-exit rows with l >= text_len (never consumed).
// ---------------------------------------------------------------------------
__global__ __launch_bounds__(320) void con_gemm(const float* __restrict__ kn,
                                                const float* __restrict__ wc,
                                                const float* __restrict__ anew,
                                                const int* __restrict__ tlen,
                                                __hip_bfloat16* __restrict__ ybar,
                                                float* __restrict__ nk_inv) {
  const int bl = blockIdx.x;
  const int b = bl / Ls, l = bl % Ls;
  if (l >= tlen[b]) return;   // block-uniform exit

  const float* __restrict__ Kb = kn + (size_t)bl * (Ns * Ds);
  const int t = threadIdx.x;

  float acc[Ns];
#pragma unroll
  for (int n = 0; n < Ns; ++n) acc[n] = 0.f;

  if (t < Ds) {
    for (int s4 = 0; s4 < Ds / 4; ++s4) {
      const float w0 = wc[(4 * s4 + 0) * Ds + t];
      const float w1 = wc[(4 * s4 + 1) * Ds + t];
      const float w2 = wc[(4 * s4 + 2) * Ds + t];
      const float w3 = wc[(4 * s4 + 3) * Ds + t];
#pragma unroll
      for (int n = 0; n < Ns; ++n) {
        const float4 kv = *reinterpret_cast<const float4*>(Kb + n * Ds + s4 * 4);
        acc[n] = fmaf(kv.x, w0, fmaf(kv.y, w1, fmaf(kv.z, w2, fmaf(kv.w, w3, acc[n]))));
      }
    }
  }

  __shared__ float Ylds[Ns][Ds];
  __shared__ float scale[Ns];
  if (t < Ds) {
#pragma unroll
    for (int n = 0; n < Ns; ++n) Ylds[n][t] = acc[n];
  }
  __syncthreads();

  const int wave = t >> 6, lane = t & 63;
  for (int n = wave; n < Ns; n += 5) {
    float sy = 0.f, sk = 0.f;
    for (int d = lane; d < Ds; d += 64) {
      const float yv = Ylds[n][d];
      sy += yv * yv;
      const float kv = Kb[n * Ds + d];
      sk += kv * kv;
    }
#pragma unroll
    for (int off = 32; off > 0; off >>= 1) {
      sy += __shfl_xor(sy, off);
      sk += __shfl_xor(sk, off);
    }
    if (lane == 0) {
      const float a = anew[(size_t)bl * Ns + n];
      const float aff = (sqrtf((a - 0.5f) * (a - 0.5f) + 0.25f * a * a) - 0.06467f) *
                        (1.0f / 0.607468f);
      const float nfv = fmaxf(aff * sqrtf(sy), EPSf);
      scale[n] = aff / nfv;
      nk_inv[(size_t)bl * Ns + n] = 1.0f / fmaxf(sqrtf(sk), EPSf);
    }
  }
  __syncthreads();

  if (t < Ds) {
#pragma unroll
    for (int n = 0; n < Ns; ++n)
      ybar[((size_t)bl * Ns + n) * Ds + t] = __float2bfloat16(Ylds[n][t] * scale[n]);
  }
}

// ---------------------------------------------------------------------------
// Kernel 4: banded contextual attention. One block per (b,j), j < len.
// 320 threads = 40 groups of 8 lanes; group g owns n=g, keeps its scaled
// K[b,j,n,:] slice in registers (no LDS in the hot loop). For each k in the
// window: cos_n = dot(ybar[b,k,n,:], K_scaled) -> |.| summed via LDS atomics.
// ---------------------------------------------------------------------------
__global__ __launch_bounds__(320) void con_attn(const float* __restrict__ kn,
                                                const unsigned short* __restrict__ ybar,
                                                const float* __restrict__ nk_inv,
                                                const int* __restrict__ tlen,
                                                float* __restrict__ out) {
  const int blk = blockIdx.x;
  const int b = blk / Ls, j = blk % Ls;
  const int len = tlen[b];
  if (j >= len) return;   // out row already zeroed by sem_attn
  const int k0 = max(j - WPc, 0);
  const int k1 = min(j + WFc, len - 1);
  const int nk = k1 - k0 + 1;

  const int g = threadIdx.x >> 3;   // n index, 0..39
  const int l = threadIdx.x & 7;

  __shared__ float lout[21];
  if (threadIdx.x < 21) lout[threadIdx.x] = 0.f;

  const int blj = b * Ls + j;
  const float* __restrict__ Krow = kn + ((size_t)blj * Ns + g) * Ds;
  const float kinv = nk_inv[(size_t)blj * Ns + g];

  float4 kreg[10];
#pragma unroll
  for (int i = 0; i < 10; ++i) {
    const int f4 = l + i * 8;
    if (f4 < Ds / 4) {
      float4 v = *reinterpret_cast<const float4*>(Krow + f4 * 4);
      v.x *= kinv; v.y *= kinv; v.z *= kinv; v.w *= kinv;
      kreg[i] = v;
    } else {
      kreg[i] = make_float4(0.f, 0.f, 0.f, 0.f);
    }
  }
  __syncthreads();

  for (int ki = 0; ki < nk; ++ki) {
    const int k = k0 + ki;
    const unsigned short* __restrict__ yrow = ybar + (((size_t)(b * Ls + k) * Ns + g) * Ds);
    float part = 0.f;
#pragma unroll
    for (int i = 0; i < 10; ++i) {
      const int f4 = l + i * 8;
      if (f4 < Ds / 4) {
        const ushort4 u = *reinterpret_cast<const ushort4*>(yrow + f4 * 4);
        const float y0 = __uint_as_float((unsigned)u.x << 16);
        const float y1 = __uint_as_float((unsigned)u.y << 16);
        const float y2 = __uint_as_float((unsigned)u.z << 16);
        const float y3 = __uint_as_float((unsigned)u.w << 16);
        part = fmaf(y0, kreg[i].x, part);
        part = fmaf(y1, kreg[i].y, part);
        part = fmaf(y2, kreg[i].z, part);
        part = fmaf(y3, kreg[i].w, part);
      }
    }
    part += __shfl_xor(part, 1);
    part += __shfl_xor(part, 2);
    part += __shfl_xor(part, 4);
    if (l == 0) atomicAdd(&lout[ki], fabsf(part));
  }
  __syncthreads();
  if ((int)threadIdx.x < nk) {
    const int k = k0 + threadIdx.x;
    out[(size_t)blj * MAXNc + k] += 5.0f * lout[threadIdx.x];  // 0.5 * 10 * sum|cos|
  }
}

// ---------------------------------------------------------------------------
extern "C" void kernel_launch(void* const* d_in, const int* in_sizes, int n_in,
                              void* d_out, int out_size, void* d_ws, size_t ws_size,
                              hipStream_t stream) {
  const float* nf   = (const float*)d_in[0];   // (B,L,G)
  const float* kn   = (const float*)d_in[1];   // (B,L,N,D)
  const float* anew = (const float*)d_in[2];   // (B,L,N)
  const float* wsem = (const float*)d_in[3];   // (G,G)
  const float* wcon = (const float*)d_in[4];   // (D,D)
  const int*   tlen = (const int*)d_in[5];     // (B,)
  float* out = (float*)d_out;

  // workspace layout (f32 elements, then bf16 tail; ~93 MB total)
  float* att_sem = (float*)d_ws;                    // 3520*512
  float* na_arr  = att_sem + (size_t)BL * Gs;       // 3520
  float* wt      = na_arr + BL;                     // 512*512
  float* nkinv   = wt + (size_t)Gs * Gs;            // 3520*40
  __hip_bfloat16* ybar = (__hip_bfloat16*)(nkinv + (size_t)BL * Ns);  // 3520*40*300 bf16

  transpose_wsem<<<dim3(16, 16), dim3(32, 8), 0, stream>>>(wsem, wt);
  sem_gemm<<<BL / 8, 512, 0, stream>>>(nf, wt, att_sem, na_arr);
  sem_attn<<<BL, 256, 0, stream>>>(nf, att_sem, na_arr, tlen, out);
  con_gemm<<<BL, 320, 0, stream>>>(kn, wcon, anew, tlen, ybar, nkinv);
  con_attn<<<BL, 320, 0, stream>>>(kn, (const unsigned short*)ybar, nkinv, tlen, out);
}

// Round 2
// 735.942 us; speedup vs baseline: 3.0554x; 3.0554x over previous
//
#include <hip/hip_runtime.h>
#include <hip/hip_bf16.h>
#include <math.h>

// Problem constants (from reference)
constexpr int Bb   = 32;
constexpr int Ls   = 110;
constexpr int Gs   = 512;
constexpr int Ns   = 40;
constexpr int Ds   = 300;
constexpr int WPc  = 10;
constexpr int WFc  = 10;
constexpr int MAXNc = 110;
constexpr float EPSf  = 1e-8f;
constexpr float CLIPf = 1.0f - 1e-6f;
constexpr int BL = Bb * Ls;        // 3520
constexpr int Mrows = BL * Ns;     // 140800 flattened GEMM rows

typedef __attribute__((ext_vector_type(8))) short short8_t;
typedef __attribute__((ext_vector_type(4))) short short4_t;
typedef __attribute__((ext_vector_type(4))) float floatx4;

__device__ __forceinline__ unsigned short bf16r(float f) {
  unsigned u = __float_as_uint(f);
  u += 0x7fffu + ((u >> 16) & 1u);          // RNE to bf16
  return (unsigned short)(u >> 16);
}

// ---------------------------------------------------------------------------
// Kernel 0: transpose W_sem (512x512) so the sem GEMM reads it coalesced.
// ---------------------------------------------------------------------------
__global__ __launch_bounds__(256) void transpose_wsem(const float* __restrict__ w,
                                                      float* __restrict__ wt) {
  __shared__ float tile[32][33];
  const int bx = blockIdx.x * 32;
  const int by = blockIdx.y * 32;
  const int tx = threadIdx.x;   // 0..31
  const int ty = threadIdx.y;   // 0..7
#pragma unroll
  for (int r = ty; r < 32; r += 8)
    tile[r][tx] = w[(by + r) * Gs + (bx + tx)];
  __syncthreads();
#pragma unroll
  for (int r = ty; r < 32; r += 8)
    wt[(bx + r) * Gs + (by + tx)] = tile[tx][r];   // wt[t][s] = w[s][t]
}

// ---------------------------------------------------------------------------
// Kernel 0b: WcT[t][s] = bf16(Wc[s][t]), zero-padded to [320][320].
// B-operand of the con MFMA GEMM wants, per lane (n=t), 8 consecutive k(=s)
// values -> contiguous reads from WcT rows. 205 KB, L2-resident.
// ---------------------------------------------------------------------------
__global__ __launch_bounds__(256) void wct_prep(const float* __restrict__ wc,
                                                short* __restrict__ wct) {
  __shared__ float tile[32][33];
  const int t0 = blockIdx.x * 32;   // t tile
  const int s0 = blockIdx.y * 32;   // s tile
  const int tx = threadIdx.x, ty = threadIdx.y;
#pragma unroll
  for (int r = ty; r < 32; r += 8) {
    const int s = s0 + r, t = t0 + tx;
    tile[r][tx] = (s < Ds && t < Ds) ? wc[s * Ds + t] : 0.f;
  }
  __syncthreads();
#pragma unroll
  for (int r = ty; r < 32; r += 8) {
    const int t = t0 + r, s = s0 + tx;
    wct[t * 320 + s] = (short)bf16r(tile[tx][r]);
  }
}

// ---------------------------------------------------------------------------
// Kernel 1: att_sem[bl,s] = sum_t W[s,t] * x[bl,t]  (= sum_t WT[t,s]*x[bl,t])
// ---------------------------------------------------------------------------
__global__ __launch_bounds__(512) void sem_gemm(const float* __restrict__ nf,
                                                const float* __restrict__ wt,
                                                float* __restrict__ att_sem,
                                                float* __restrict__ na_arr) {
  const int bl0 = blockIdx.x * 8;
  const int s = threadIdx.x;
  const float* __restrict__ x0 = nf + (size_t)bl0 * Gs;
  float acc[8];
#pragma unroll
  for (int r = 0; r < 8; ++r) acc[r] = 0.f;
#pragma unroll 4
  for (int t = 0; t < Gs; ++t) {
    const float wv = wt[t * Gs + s];
#pragma unroll
    for (int r = 0; r < 8; ++r) acc[r] = fmaf(wv, x0[r * Gs + t], acc[r]);
  }
#pragma unroll
  for (int r = 0; r < 8; ++r) att_sem[(size_t)(bl0 + r) * Gs + s] = acc[r];

  __shared__ float partial[8][8];
  const int wave = s >> 6, lane = s & 63;
#pragma unroll
  for (int r = 0; r < 8; ++r) {
    float v = acc[r] * acc[r];
#pragma unroll
    for (int off = 32; off > 0; off >>= 1) v += __shfl_xor(v, off);
    if (lane == 0) partial[r][wave] = v;
  }
  __syncthreads();
  if (s < 8) {
    float sum = 0.f;
#pragma unroll
    for (int w2 = 0; w2 < 8; ++w2) sum += partial[s][w2];
    na_arr[bl0 + s] = fmaxf(sqrtf(sum), EPSf);
  }
}

// ---------------------------------------------------------------------------
// Kernel 2: banded semantic attention + softmax. One block per (b,j).
// Writes the FULL output row (zeros outside window) -> serves as out init.
// ---------------------------------------------------------------------------
__global__ __launch_bounds__(256) void sem_attn(const float* __restrict__ nf,
                                                const float* __restrict__ att_sem,
                                                const float* __restrict__ na_arr,
                                                const int* __restrict__ tlen,
                                                float* __restrict__ out) {
  const int blk = blockIdx.x;
  const int b = blk / Ls, j = blk % Ls;
  const int len = tlen[b];
  float* __restrict__ orow = out + (size_t)(b * Ls + j) * MAXNc;
  if (j >= len) {
    for (int k = threadIdx.x; k < MAXNc; k += 256) orow[k] = 0.f;
    return;
  }
  const int k0 = max(j - WPc, 0);
  const int k1 = min(j + WFc, len - 1);
  const int nk = k1 - k0 + 1;   // <= 21

  __shared__ float xs[Gs];
  __shared__ float sc[21];
  __shared__ float red[4];

  const float* __restrict__ x = nf + (size_t)(b * Ls + j) * Gs;
  float ss = 0.f;
  for (int t = threadIdx.x; t < Gs; t += 256) {
    const float v = x[t];
    xs[t] = v;
    ss += v * v;
  }
  const int wave = threadIdx.x >> 6, lane = threadIdx.x & 63;
#pragma unroll
  for (int off = 32; off > 0; off >>= 1) ss += __shfl_xor(ss, off);
  if (lane == 0) red[wave] = ss;
  __syncthreads();
  const float nfn = fmaxf(sqrtf(red[0] + red[1] + red[2] + red[3]), EPSf);

  for (int i = wave; i < nk; i += 4) {
    const int k = k0 + i;
    const float* __restrict__ as = att_sem + (size_t)(b * Ls + k) * Gs;
    float d = 0.f;
#pragma unroll
    for (int t = lane; t < Gs; t += 64) d = fmaf(xs[t], as[t], d);
#pragma unroll
    for (int off = 32; off > 0; off >>= 1) d += __shfl_xor(d, off);
    if (lane == 0) {
      float cs = d / (nfn * na_arr[b * Ls + k]);
      cs = fminf(fmaxf(cs, -CLIPf), CLIPf);
      sc[i] = 1.0f - acosf(cs) * (float)(1.0 / M_PI);
    }
  }
  __syncthreads();
  if (threadIdx.x == 0) {
    float m = -1e30f;
    for (int i = 0; i < nk; ++i) m = fmaxf(m, sc[i]);
    red[0] = m;
  }
  __syncthreads();
  const float m = red[0];
  if ((int)threadIdx.x < nk) sc[threadIdx.x] = expf(sc[threadIdx.x] - m);
  __syncthreads();
  if (threadIdx.x == 0) {
    float s = 0.f;
    for (int i = 0; i < nk; ++i) s += sc[i];
    red[1] = 1.0f / fmaxf(s, EPSf);
  }
  __syncthreads();
  const float inv = red[1];
  for (int k = threadIdx.x; k < MAXNc; k += 256) {
    float v = 0.f;
    if (k >= k0 && k <= k1) v = 0.5f * sc[k - k0] * inv;
    orow[k] = v;
  }
}

// ---------------------------------------------------------------------------
// Kernel 3: flattened MFMA GEMM  Y[Mrows x 300] = K[Mrows x 300] . Wc[300x300]
// then row-normalize (aff/||aff*Y||) and store bf16 ybar.
// WG = 256 thr (4 waves). M-tile 64 rows (4 x 16x16 tiles / wave), waves
// partition N: wave w owns cols [w*80, w*80+80) (5 x 16 tiles; N padded 320).
// A staged in LDS bf16 (row pitch 40 -> 2-way-at-most bank aliasing);
// B frags read directly from L2-resident WcT. Memory-bound by design:
// ~190 MB HBM vs ~91 clk/SIMD of MFMA per k-chunk.
// ---------------------------------------------------------------------------
__global__ __launch_bounds__(256) void con_gemm_mfma(const float* __restrict__ kn,
                                                     const short* __restrict__ wct,
                                                     const float* __restrict__ anew,
                                                     const int* __restrict__ tlen,
                                                     unsigned short* __restrict__ ybar) {
  const int row0 = blockIdx.x * 64;
  {
    // dead-block skip: rows map to (bl = row/40); alive iff l < tlen[b]
    const int bl0 = row0 / Ns, bl1 = (row0 + 63) / Ns;
    bool alive = false;
    for (int bl = bl0; bl <= bl1; ++bl)
      if ((bl % Ls) < tlen[bl / Ls]) alive = true;
    if (!alive) return;
  }

  __shared__ short A_lds[64 * 40];   // 64 rows x 32 bf16, pitch 40 (80 B)
  __shared__ float rowss[64][4];
  __shared__ float scl[64];

  const int tid = threadIdx.x;
  const int wave = tid >> 6, lane = tid & 63;
  const int quad = lane >> 4, l16 = lane & 15;

  floatx4 acc[4][5];
#pragma unroll
  for (int mt = 0; mt < 4; ++mt)
#pragma unroll
    for (int i = 0; i < 5; ++i) acc[mt][i] = (floatx4){0.f, 0.f, 0.f, 0.f};

  const int r_st = tid >> 3;        // staging row (0..31), +32 for 2nd half
  const int pos = tid & 7;          // float4 slot within the 32-wide chunk

  for (int c = 0; c < 10; ++c) {
    // ---- stage A chunk: K[row0..row0+63][c*32 .. c*32+31] f32 -> bf16 LDS
    const int k0 = c * 32 + pos * 4;
#pragma unroll
    for (int half = 0; half < 2; ++half) {
      const int r = r_st + half * 32;
      float4 v = make_float4(0.f, 0.f, 0.f, 0.f);
      if (k0 < Ds)   // k0 <= 296 when valid; k0+3 <= 299 in-bounds
        v = *reinterpret_cast<const float4*>(kn + (size_t)(row0 + r) * Ds + k0);
      short4_t p;
      p.x = (short)bf16r(v.x);
      p.y = (short)bf16r(v.y);
      p.z = (short)bf16r(v.z);
      p.w = (short)bf16r(v.w);
      *reinterpret_cast<short4_t*>(&A_lds[r * 40 + pos * 4]) = p;
    }
    __syncthreads();

    // ---- B fragments straight from L2 (WcT rows contiguous in k)
    short8_t bfrag[5];
#pragma unroll
    for (int i = 0; i < 5; ++i) {
      const int t = wave * 80 + i * 16 + l16;
      bfrag[i] = *reinterpret_cast<const short8_t*>(wct + t * 320 + c * 32 + quad * 8);
    }
#pragma unroll
    for (int mt = 0; mt < 4; ++mt) {
      const short8_t afrag =
          *reinterpret_cast<const short8_t*>(&A_lds[(mt * 16 + l16) * 40 + quad * 8]);
#pragma unroll
      for (int i = 0; i < 5; ++i)
        acc[mt][i] = __builtin_amdgcn_mfma_f32_16x16x32_bf16(afrag, bfrag[i], acc[mt][i], 0, 0, 0);
    }
    __syncthreads();
  }

  // ---- row sum-of-squares: reduce over this wave's 16-col groups, then LDS
#pragma unroll
  for (int mt = 0; mt < 4; ++mt) {
#pragma unroll
    for (int r = 0; r < 4; ++r) {
      float p = 0.f;
#pragma unroll
      for (int i = 0; i < 5; ++i) {
        const float y = acc[mt][i][r];
        p = fmaf(y, y, p);
      }
      p += __shfl_xor(p, 1);
      p += __shfl_xor(p, 2);
      p += __shfl_xor(p, 4);
      p += __shfl_xor(p, 8);
      if (l16 == 0) rowss[mt * 16 + quad * 4 + r][wave] = p;
    }
  }
  __syncthreads();
  if (tid < 64) {
    const float ss = rowss[tid][0] + rowss[tid][1] + rowss[tid][2] + rowss[tid][3];
    const float a = anew[row0 + tid];
    const float aff = (sqrtf((a - 0.5f) * (a - 0.5f) + 0.25f * a * a) - 0.06467f) *
                      (1.0f / 0.607468f);
    scl[tid] = aff / fmaxf(aff * sqrtf(ss), EPSf);   // aff > 0 always
  }
  __syncthreads();

  // ---- scale + bf16 store (C layout: col = lane&15, row = quad*4+reg)
#pragma unroll
  for (int mt = 0; mt < 4; ++mt) {
#pragma unroll
    for (int i = 0; i < 5; ++i) {
      const int col = wave * 80 + i * 16 + l16;
      if (col < Ds) {
#pragma unroll
        for (int r = 0; r < 4; ++r) {
          const int row = mt * 16 + quad * 4 + r;
          ybar[(size_t)(row0 + row) * Ds + col] = bf16r(acc[mt][i][r] * scl[row]);
        }
      }
    }
  }
}

// ---------------------------------------------------------------------------
// Kernel 4: banded contextual attention. One block per (b,j), j < len.
// 320 threads = 40 groups of 8 lanes; group g owns n=g. Computes 1/||K||
// locally from its registers (nk_inv array eliminated).
// ---------------------------------------------------------------------------
__global__ __launch_bounds__(320) void con_attn(const float* __restrict__ kn,
                                                const unsigned short* __restrict__ ybar,
                                                const int* __restrict__ tlen,
                                                float* __restrict__ out) {
  const int blk = blockIdx.x;
  const int b = blk / Ls, j = blk % Ls;
  const int len = tlen[b];
  if (j >= len) return;   // out row already zeroed by sem_attn
  const int k0 = max(j - WPc, 0);
  const int k1 = min(j + WFc, len - 1);
  const int nk = k1 - k0 + 1;

  const int g = threadIdx.x >> 3;   // n index, 0..39
  const int l = threadIdx.x & 7;

  __shared__ float lout[21];
  if (threadIdx.x < 21) lout[threadIdx.x] = 0.f;

  const int blj = b * Ls + j;
  const float* __restrict__ Krow = kn + ((size_t)blj * Ns + g) * Ds;

  float4 kreg[10];
  float sk = 0.f;
#pragma unroll
  for (int i = 0; i < 10; ++i) {
    const int f4 = l + i * 8;
    if (f4 < Ds / 4) {
      const float4 v = *reinterpret_cast<const float4*>(Krow + f4 * 4);
      sk = fmaf(v.x, v.x, fmaf(v.y, v.y, fmaf(v.z, v.z, fmaf(v.w, v.w, sk))));
      kreg[i] = v;
    } else {
      kreg[i] = make_float4(0.f, 0.f, 0.f, 0.f);
    }
  }
  sk += __shfl_xor(sk, 1);
  sk += __shfl_xor(sk, 2);
  sk += __shfl_xor(sk, 4);
  const float kinv = 1.0f / fmaxf(sqrtf(sk), EPSf);
#pragma unroll
  for (int i = 0; i < 10; ++i) {
    kreg[i].x *= kinv; kreg[i].y *= kinv; kreg[i].z *= kinv; kreg[i].w *= kinv;
  }
  __syncthreads();

  for (int ki = 0; ki < nk; ++ki) {
    const int k = k0 + ki;
    const unsigned short* __restrict__ yrow = ybar + (((size_t)(b * Ls + k) * Ns + g) * Ds);
    float part = 0.f;
#pragma unroll
    for (int i = 0; i < 10; ++i) {
      const int f4 = l + i * 8;
      if (f4 < Ds / 4) {
        const ushort4 u = *reinterpret_cast<const ushort4*>(yrow + f4 * 4);
        part = fmaf(__uint_as_float((unsigned)u.x << 16), kreg[i].x, part);
        part = fmaf(__uint_as_float((unsigned)u.y << 16), kreg[i].y, part);
        part = fmaf(__uint_as_float((unsigned)u.z << 16), kreg[i].z, part);
        part = fmaf(__uint_as_float((unsigned)u.w << 16), kreg[i].w, part);
      }
    }
    part += __shfl_xor(part, 1);
    part += __shfl_xor(part, 2);
    part += __shfl_xor(part, 4);
    if (l == 0) atomicAdd(&lout[ki], fabsf(part));
  }
  __syncthreads();
  if ((int)threadIdx.x < nk) {
    const int k = k0 + threadIdx.x;
    out[(size_t)blj * MAXNc + k] += 5.0f * lout[threadIdx.x];  // 0.5 * 10 * sum|cos|
  }
}

// ---------------------------------------------------------------------------
extern "C" void kernel_launch(void* const* d_in, const int* in_sizes, int n_in,
                              void* d_out, int out_size, void* d_ws, size_t ws_size,
                              hipStream_t stream) {
  const float* nf   = (const float*)d_in[0];   // (B,L,G)
  const float* kn   = (const float*)d_in[1];   // (B,L,N,D)
  const float* anew = (const float*)d_in[2];   // (B,L,N)
  const float* wsem = (const float*)d_in[3];   // (G,G)
  const float* wcon = (const float*)d_in[4];   // (D,D)
  const int*   tlen = (const int*)d_in[5];     // (B,)
  float* out = (float*)d_out;

  // workspace layout (~93 MB)
  float* att_sem = (float*)d_ws;                         // 3520*512 f32
  float* na_arr  = att_sem + (size_t)BL * Gs;            // 3520 f32
  float* wt      = na_arr + BL;                          // 512*512 f32
  short* wct     = (short*)(wt + (size_t)Gs * Gs);       // 320*320 bf16
  unsigned short* ybar = (unsigned short*)(wct + 320 * 320);  // Mrows*300 bf16

  transpose_wsem<<<dim3(16, 16), dim3(32, 8), 0, stream>>>(wsem, wt);
  wct_prep<<<dim3(10, 10), dim3(32, 8), 0, stream>>>(wcon, wct);
  sem_gemm<<<BL / 8, 512, 0, stream>>>(nf, wt, att_sem, na_arr);
  sem_attn<<<BL, 256, 0, stream>>>(nf, att_sem, na_arr, tlen, out);
  con_gemm_mfma<<<Mrows / 64, 256, 0, stream>>>(kn, wct, anew, tlen, ybar);
  con_attn<<<BL, 320, 0, stream>>>(kn, ybar, tlen, out);
}

// Round 3
// 508.164 us; speedup vs baseline: 4.4249x; 1.4482x over previous
//
#include <hip/hip_runtime.h>
#include <hip/hip_bf16.h>
#include <math.h>

// Problem constants (from reference)
constexpr int Bb   = 32;
constexpr int Ls   = 110;
constexpr int Gs   = 512;
constexpr int Ns   = 40;
constexpr int Ds   = 300;
constexpr int WPc  = 10;
constexpr int WFc  = 10;
constexpr int MAXNc = 110;
constexpr float EPSf  = 1e-8f;
constexpr float CLIPf = 1.0f - 1e-6f;
constexpr int BL = Bb * Ls;        // 3520
constexpr int Mrows = BL * Ns;     // 140800 flattened GEMM rows

typedef __attribute__((ext_vector_type(8))) short short8_t;
typedef __attribute__((ext_vector_type(4))) short short4_t;
typedef __attribute__((ext_vector_type(4))) float floatx4;

__device__ __forceinline__ unsigned short bf16r(float f) {
  unsigned u = __float_as_uint(f);
  u += 0x7fffu + ((u >> 16) & 1u);          // RNE to bf16
  return (unsigned short)(u >> 16);
}

// ---------------------------------------------------------------------------
// Kernel 0: transpose W_sem (512x512) so the sem GEMM reads it coalesced.
// ---------------------------------------------------------------------------
__global__ __launch_bounds__(256) void transpose_wsem(const float* __restrict__ w,
                                                      float* __restrict__ wt) {
  __shared__ float tile[32][33];
  const int bx = blockIdx.x * 32;
  const int by = blockIdx.y * 32;
  const int tx = threadIdx.x;   // 0..31
  const int ty = threadIdx.y;   // 0..7
#pragma unroll
  for (int r = ty; r < 32; r += 8)
    tile[r][tx] = w[(by + r) * Gs + (bx + tx)];
  __syncthreads();
#pragma unroll
  for (int r = ty; r < 32; r += 8)
    wt[(bx + r) * Gs + (by + tx)] = tile[tx][r];   // wt[t][s] = w[s][t]
}

// ---------------------------------------------------------------------------
// Kernel 0b: WcT[t][s] = bf16(Wc[s][t]), zero-padded to [320][320].
// ---------------------------------------------------------------------------
__global__ __launch_bounds__(256) void wct_prep(const float* __restrict__ wc,
                                                short* __restrict__ wct) {
  __shared__ float tile[32][33];
  const int t0 = blockIdx.x * 32;   // t tile
  const int s0 = blockIdx.y * 32;   // s tile
  const int tx = threadIdx.x, ty = threadIdx.y;
#pragma unroll
  for (int r = ty; r < 32; r += 8) {
    const int s = s0 + r, t = t0 + tx;
    tile[r][tx] = (s < Ds && t < Ds) ? wc[s * Ds + t] : 0.f;
  }
  __syncthreads();
#pragma unroll
  for (int r = ty; r < 32; r += 8) {
    const int t = t0 + r, s = s0 + tx;
    wct[t * 320 + s] = (short)bf16r(tile[tx][r]);
  }
}

// ---------------------------------------------------------------------------
// Kernel 1: att_sem[bl,s] = sum_t W[s,t] * x[bl,t]
// ---------------------------------------------------------------------------
__global__ __launch_bounds__(512) void sem_gemm(const float* __restrict__ nf,
                                                const float* __restrict__ wt,
                                                float* __restrict__ att_sem,
                                                float* __restrict__ na_arr) {
  const int bl0 = blockIdx.x * 8;
  const int s = threadIdx.x;
  const float* __restrict__ x0 = nf + (size_t)bl0 * Gs;
  float acc[8];
#pragma unroll
  for (int r = 0; r < 8; ++r) acc[r] = 0.f;
#pragma unroll 4
  for (int t = 0; t < Gs; ++t) {
    const float wv = wt[t * Gs + s];
#pragma unroll
    for (int r = 0; r < 8; ++r) acc[r] = fmaf(wv, x0[r * Gs + t], acc[r]);
  }
#pragma unroll
  for (int r = 0; r < 8; ++r) att_sem[(size_t)(bl0 + r) * Gs + s] = acc[r];

  __shared__ float partial[8][8];
  const int wave = s >> 6, lane = s & 63;
#pragma unroll
  for (int r = 0; r < 8; ++r) {
    float v = acc[r] * acc[r];
#pragma unroll
    for (int off = 32; off > 0; off >>= 1) v += __shfl_xor(v, off);
    if (lane == 0) partial[r][wave] = v;
  }
  __syncthreads();
  if (s < 8) {
    float sum = 0.f;
#pragma unroll
    for (int w2 = 0; w2 < 8; ++w2) sum += partial[s][w2];
    na_arr[bl0 + s] = fmaxf(sqrtf(sum), EPSf);
  }
}

// ---------------------------------------------------------------------------
// Kernel 2: banded semantic attention + softmax. One block per (b,j).
// Writes the FULL output row (zeros outside window) -> serves as out init.
// ---------------------------------------------------------------------------
__global__ __launch_bounds__(256) void sem_attn(const float* __restrict__ nf,
                                                const float* __restrict__ att_sem,
                                                const float* __restrict__ na_arr,
                                                const int* __restrict__ tlen,
                                                float* __restrict__ out) {
  const int blk = blockIdx.x;
  const int b = blk / Ls, j = blk % Ls;
  const int len = tlen[b];
  float* __restrict__ orow = out + (size_t)(b * Ls + j) * MAXNc;
  if (j >= len) {
    for (int k = threadIdx.x; k < MAXNc; k += 256) orow[k] = 0.f;
    return;
  }
  const int k0 = max(j - WPc, 0);
  const int k1 = min(j + WFc, len - 1);
  const int nk = k1 - k0 + 1;   // <= 21

  __shared__ float xs[Gs];
  __shared__ float sc[21];
  __shared__ float red[4];

  const float* __restrict__ x = nf + (size_t)(b * Ls + j) * Gs;
  float ss = 0.f;
  for (int t = threadIdx.x; t < Gs; t += 256) {
    const float v = x[t];
    xs[t] = v;
    ss += v * v;
  }
  const int wave = threadIdx.x >> 6, lane = threadIdx.x & 63;
#pragma unroll
  for (int off = 32; off > 0; off >>= 1) ss += __shfl_xor(ss, off);
  if (lane == 0) red[wave] = ss;
  __syncthreads();
  const float nfn = fmaxf(sqrtf(red[0] + red[1] + red[2] + red[3]), EPSf);

  for (int i = wave; i < nk; i += 4) {
    const int k = k0 + i;
    const float* __restrict__ as = att_sem + (size_t)(b * Ls + k) * Gs;
    float d = 0.f;
#pragma unroll
    for (int t = lane; t < Gs; t += 64) d = fmaf(xs[t], as[t], d);
#pragma unroll
    for (int off = 32; off > 0; off >>= 1) d += __shfl_xor(d, off);
    if (lane == 0) {
      float cs = d / (nfn * na_arr[b * Ls + k]);
      cs = fminf(fmaxf(cs, -CLIPf), CLIPf);
      sc[i] = 1.0f - acosf(cs) * (float)(1.0 / M_PI);
    }
  }
  __syncthreads();
  if (threadIdx.x == 0) {
    float m = -1e30f;
    for (int i = 0; i < nk; ++i) m = fmaxf(m, sc[i]);
    red[0] = m;
  }
  __syncthreads();
  const float m = red[0];
  if ((int)threadIdx.x < nk) sc[threadIdx.x] = expf(sc[threadIdx.x] - m);
  __syncthreads();
  if (threadIdx.x == 0) {
    float s = 0.f;
    for (int i = 0; i < nk; ++i) s += sc[i];
    red[1] = 1.0f / fmaxf(s, EPSf);
  }
  __syncthreads();
  const float inv = red[1];
  for (int k = threadIdx.x; k < MAXNc; k += 256) {
    float v = 0.f;
    if (k >= k0 && k <= k1) v = 0.5f * sc[k - k0] * inv;
    orow[k] = v;
  }
}

// ---------------------------------------------------------------------------
// Kernel 3: flattened MFMA GEMM  Y[Mrows x 300] = K[Mrows x 300] . Wc[300x300]
// then row-normalize (aff/||aff*Y||) and store bf16 ybar (pitch 300).
// ---------------------------------------------------------------------------
__global__ __launch_bounds__(256) void con_gemm_mfma(const float* __restrict__ kn,
                                                     const short* __restrict__ wct,
                                                     const float* __restrict__ anew,
                                                     const int* __restrict__ tlen,
                                                     unsigned short* __restrict__ ybar) {
  const int row0 = blockIdx.x * 64;
  {
    const int bl0 = row0 / Ns, bl1 = (row0 + 63) / Ns;
    bool alive = false;
    for (int bl = bl0; bl <= bl1; ++bl)
      if ((bl % Ls) < tlen[bl / Ls]) alive = true;
    if (!alive) return;
  }

  __shared__ short A_lds[64 * 40];   // 64 rows x 32 bf16, pitch 40 (80 B)
  __shared__ float rowss[64][4];
  __shared__ float scl[64];

  const int tid = threadIdx.x;
  const int wave = tid >> 6, lane = tid & 63;
  const int quad = lane >> 4, l16 = lane & 15;

  floatx4 acc[4][5];
#pragma unroll
  for (int mt = 0; mt < 4; ++mt)
#pragma unroll
    for (int i = 0; i < 5; ++i) acc[mt][i] = (floatx4){0.f, 0.f, 0.f, 0.f};

  const int r_st = tid >> 3;        // staging row (0..31), +32 for 2nd half
  const int pos = tid & 7;          // float4 slot within the 32-wide chunk

  for (int c = 0; c < 10; ++c) {
    const int k0 = c * 32 + pos * 4;
#pragma unroll
    for (int half = 0; half < 2; ++half) {
      const int r = r_st + half * 32;
      float4 v = make_float4(0.f, 0.f, 0.f, 0.f);
      if (k0 < Ds)
        v = *reinterpret_cast<const float4*>(kn + (size_t)(row0 + r) * Ds + k0);
      short4_t p;
      p.x = (short)bf16r(v.x);
      p.y = (short)bf16r(v.y);
      p.z = (short)bf16r(v.z);
      p.w = (short)bf16r(v.w);
      *reinterpret_cast<short4_t*>(&A_lds[r * 40 + pos * 4]) = p;
    }
    __syncthreads();

    short8_t bfrag[5];
#pragma unroll
    for (int i = 0; i < 5; ++i) {
      const int t = wave * 80 + i * 16 + l16;
      bfrag[i] = *reinterpret_cast<const short8_t*>(wct + t * 320 + c * 32 + quad * 8);
    }
#pragma unroll
    for (int mt = 0; mt < 4; ++mt) {
      const short8_t afrag =
          *reinterpret_cast<const short8_t*>(&A_lds[(mt * 16 + l16) * 40 + quad * 8]);
#pragma unroll
      for (int i = 0; i < 5; ++i)
        acc[mt][i] = __builtin_amdgcn_mfma_f32_16x16x32_bf16(afrag, bfrag[i], acc[mt][i], 0, 0, 0);
    }
    __syncthreads();
  }

#pragma unroll
  for (int mt = 0; mt < 4; ++mt) {
#pragma unroll
    for (int r = 0; r < 4; ++r) {
      float p = 0.f;
#pragma unroll
      for (int i = 0; i < 5; ++i) {
        const float y = acc[mt][i][r];
        p = fmaf(y, y, p);
      }
      p += __shfl_xor(p, 1);
      p += __shfl_xor(p, 2);
      p += __shfl_xor(p, 4);
      p += __shfl_xor(p, 8);
      if (l16 == 0) rowss[mt * 16 + quad * 4 + r][wave] = p;
    }
  }
  __syncthreads();
  if (tid < 64) {
    const float ss = rowss[tid][0] + rowss[tid][1] + rowss[tid][2] + rowss[tid][3];
    const float a = anew[row0 + tid];
    const float aff = (sqrtf((a - 0.5f) * (a - 0.5f) + 0.25f * a * a) - 0.06467f) *
                      (1.0f / 0.607468f);
    scl[tid] = aff / fmaxf(aff * sqrtf(ss), EPSf);   // aff > 0 always
  }
  __syncthreads();

#pragma unroll
  for (int mt = 0; mt < 4; ++mt) {
#pragma unroll
    for (int i = 0; i < 5; ++i) {
      const int col = wave * 80 + i * 16 + l16;
      if (col < Ds) {
#pragma unroll
        for (int r = 0; r < 4; ++r) {
          const int row = mt * 16 + quad * 4 + r;
          ybar[(size_t)(row0 + row) * Ds + col] = bf16r(acc[mt][i][r] * scl[row]);
        }
      }
    }
  }
}

// ---------------------------------------------------------------------------
// Kernel 4: banded contextual attention via MFMA banded Gram.
// Block = (b, j-tile of 16); 512 thr = 8 waves, wave w handles n = w+8i.
// Per n: A = K[b, j0..j0+15, n, :] (f32 -> bf16 in-flight, row ssq -> kinv),
// B = ybar rows k in [kbase, kbase+48) covering the +-10 band; 3 16x16 tiles.
// out[j,k] += 5 * sum_n kinv[j,n]*|S_n[j,k]| (kinv > 0 commutes with abs).
// Cross-wave reduce in LDS; single writer per (j,k).
// ---------------------------------------------------------------------------
__global__ __launch_bounds__(512) void con_attn_mfma(const float* __restrict__ kn,
                                                     const unsigned short* __restrict__ ybar,
                                                     const int* __restrict__ tlen,
                                                     float* __restrict__ out) {
  const int b = blockIdx.x / 7;
  const int jt = blockIdx.x % 7;
  const int j0 = jt * 16;
  const int len = tlen[b];
  if (j0 >= len) return;                       // rows already zeroed by sem_attn
  const int kbase = min(max(j0 - WPc, 0), Ls - 48);   // 48-window always in-range

  const int tid = threadIdx.x;
  const int wave = tid >> 6, lane = tid & 63;
  const int quad = lane >> 4, l16 = lane & 15;

  __shared__ float red[8][768];   // 24 KB: per-wave partial 16x48 tiles

  const int jj = min(j0 + l16, Ls - 1);        // A-row clamp (tile may overhang L)
  const size_t blj = (size_t)(b * Ls + jj);

  float outacc[3][4];
#pragma unroll
  for (int t = 0; t < 3; ++t)
#pragma unroll
    for (int r = 0; r < 4; ++r) outacc[t][r] = 0.f;

  // B row pointers (k rows fixed for whole block; clamped kbase keeps in-range)
  const unsigned short* yrow[3];
#pragma unroll
  for (int t = 0; t < 3; ++t) {
    const int k = kbase + t * 16 + l16;
    yrow[t] = ybar + ((size_t)(b * Ls + k) * Ns) * Ds;
  }

  for (int ni = 0; ni < 5; ++ni) {
    const int n = wave + ni * 8;
    const float* __restrict__ arow = kn + (blj * Ns + n) * Ds;

    floatx4 S[3];
#pragma unroll
    for (int t = 0; t < 3; ++t) S[t] = (floatx4){0.f, 0.f, 0.f, 0.f};
    float ssq = 0.f;

#pragma unroll
    for (int c = 0; c < 10; ++c) {
      const int d0 = c * 32 + quad * 8;
      // ---- A fragment: 8 f32 (masked tail), ssq accumulate, cvt bf16
      float av[8];
      if (c < 9) {
        const float4 v0 = *reinterpret_cast<const float4*>(arow + d0);
        const float4 v1 = *reinterpret_cast<const float4*>(arow + d0 + 4);
        av[0] = v0.x; av[1] = v0.y; av[2] = v0.z; av[3] = v0.w;
        av[4] = v1.x; av[5] = v1.y; av[6] = v1.z; av[7] = v1.w;
      } else {
        // valid d: 288..299
        if (quad == 0) {
          const float4 v0 = *reinterpret_cast<const float4*>(arow + d0);
          const float4 v1 = *reinterpret_cast<const float4*>(arow + d0 + 4);
          av[0] = v0.x; av[1] = v0.y; av[2] = v0.z; av[3] = v0.w;
          av[4] = v1.x; av[5] = v1.y; av[6] = v1.z; av[7] = v1.w;
        } else if (quad == 1) {
          const float4 v0 = *reinterpret_cast<const float4*>(arow + d0);  // 296..299
          av[0] = v0.x; av[1] = v0.y; av[2] = v0.z; av[3] = v0.w;
          av[4] = av[5] = av[6] = av[7] = 0.f;
        } else {
#pragma unroll
          for (int e = 0; e < 8; ++e) av[e] = 0.f;
        }
      }
      short8_t afrag;
#pragma unroll
      for (int e = 0; e < 8; ++e) {
        ssq = fmaf(av[e], av[e], ssq);
        afrag[e] = (short)bf16r(av[e]);
      }
      // ---- B fragments + MFMA
#pragma unroll
      for (int t = 0; t < 3; ++t) {
        const unsigned short* yr = yrow[t] + (size_t)n * Ds;
        short8_t bfrag;
        if (c < 9) {
          const short4_t u0 = *reinterpret_cast<const short4_t*>(yr + d0);
          const short4_t u1 = *reinterpret_cast<const short4_t*>(yr + d0 + 4);
          bfrag[0] = u0.x; bfrag[1] = u0.y; bfrag[2] = u0.z; bfrag[3] = u0.w;
          bfrag[4] = u1.x; bfrag[5] = u1.y; bfrag[6] = u1.z; bfrag[7] = u1.w;
        } else {
          if (quad == 0) {
            const short4_t u0 = *reinterpret_cast<const short4_t*>(yr + d0);
            const short4_t u1 = *reinterpret_cast<const short4_t*>(yr + d0 + 4);
            bfrag[0] = u0.x; bfrag[1] = u0.y; bfrag[2] = u0.z; bfrag[3] = u0.w;
            bfrag[4] = u1.x; bfrag[5] = u1.y; bfrag[6] = u1.z; bfrag[7] = u1.w;
          } else if (quad == 1) {
            const short4_t u0 = *reinterpret_cast<const short4_t*>(yr + d0);
            bfrag[0] = u0.x; bfrag[1] = u0.y; bfrag[2] = u0.z; bfrag[3] = u0.w;
            bfrag[4] = bfrag[5] = bfrag[6] = bfrag[7] = 0;
          } else {
#pragma unroll
            for (int e = 0; e < 8; ++e) bfrag[e] = 0;
          }
        }
        S[t] = __builtin_amdgcn_mfma_f32_16x16x32_bf16(afrag, bfrag, S[t], 0, 0, 0);
      }
    }

    // row ssq: butterfly over quads -> every lane holds ssq of row l16
    ssq += __shfl_xor(ssq, 16);
    ssq += __shfl_xor(ssq, 32);
    const float kinv = 1.0f / fmaxf(sqrtf(ssq), EPSf);

    // accumulate kinv[row]*|S|; C-layout row = quad*4+r lives in lane l16=row
#pragma unroll
    for (int r = 0; r < 4; ++r) {
      const float kv = __shfl(kinv, quad * 4 + r);
#pragma unroll
      for (int t = 0; t < 3; ++t)
        outacc[t][r] = fmaf(kv, fabsf(S[t][r]), outacc[t][r]);
    }
  }

  // per-wave partial tiles -> LDS
#pragma unroll
  for (int t = 0; t < 3; ++t)
#pragma unroll
    for (int r = 0; r < 4; ++r)
      red[wave][(quad * 4 + r) * 48 + t * 16 + l16] = outacc[t][r];
  __syncthreads();

  for (int idx = tid; idx < 768; idx += 512) {
    float s = 0.f;
#pragma unroll
    for (int w = 0; w < 8; ++w) s += red[w][idx];
    const int j = j0 + idx / 48;
    const int k = kbase + idx % 48;
    if (j < len && k < len && k >= j - WPc && k <= j + WFc)
      out[(size_t)(b * Ls + j) * MAXNc + k] += 5.0f * s;   // 0.5 * 10
  }
}

// ---------------------------------------------------------------------------
extern "C" void kernel_launch(void* const* d_in, const int* in_sizes, int n_in,
                              void* d_out, int out_size, void* d_ws, size_t ws_size,
                              hipStream_t stream) {
  const float* nf   = (const float*)d_in[0];   // (B,L,G)
  const float* kn   = (const float*)d_in[1];   // (B,L,N,D)
  const float* anew = (const float*)d_in[2];   // (B,L,N)
  const float* wsem = (const float*)d_in[3];   // (G,G)
  const float* wcon = (const float*)d_in[4];   // (D,D)
  const int*   tlen = (const int*)d_in[5];     // (B,)
  float* out = (float*)d_out;

  // workspace layout (~93 MB)
  float* att_sem = (float*)d_ws;                         // 3520*512 f32
  float* na_arr  = att_sem + (size_t)BL * Gs;            // 3520 f32
  float* wt      = na_arr + BL;                          // 512*512 f32
  short* wct     = (short*)(wt + (size_t)Gs * Gs);       // 320*320 bf16
  unsigned short* ybar = (unsigned short*)(wct + 320 * 320);  // Mrows*300 bf16

  transpose_wsem<<<dim3(16, 16), dim3(32, 8), 0, stream>>>(wsem, wt);
  wct_prep<<<dim3(10, 10), dim3(32, 8), 0, stream>>>(wcon, wct);
  sem_gemm<<<BL / 8, 512, 0, stream>>>(nf, wt, att_sem, na_arr);
  sem_attn<<<BL, 256, 0, stream>>>(nf, att_sem, na_arr, tlen, out);
  con_gemm_mfma<<<Mrows / 64, 256, 0, stream>>>(kn, wct, anew, tlen, ybar);
  con_attn_mfma<<<Bb * 7, 512, 0, stream>>>(kn, ybar, tlen, out);
}